// Round 10
// baseline (757.644 us; speedup 1.0000x reference)
//
#include <hip/hip_runtime.h>

typedef unsigned short u16;
typedef __attribute__((ext_vector_type(8))) short short8;
typedef __attribute__((ext_vector_type(4))) float f32x4;

#define NROW 8192

__device__ __forceinline__ float bf2f(u16 h) {
  unsigned u = ((unsigned)h) << 16;
  return __builtin_bit_cast(float, u);
}
// mode-aware load: f32 ? fp32 storage : bf16 storage (upcast)
__device__ __forceinline__ float ldf(const void* p, size_t i, int f32) {
  return f32 ? ((const float*)p)[i] : bf2f(((const u16*)p)[i]);
}
// fp32 -> bf16 round-to-nearest-even
__device__ __forceinline__ u16 f2bf(float f) {
  unsigned b = __builtin_bit_cast(unsigned, f);
  b += 0x7FFFu + ((b >> 16) & 1u);
  return (u16)(b >> 16);
}

// ---- storage-dtype detection on x (N(0,1)).
__global__ void detect3(const u16* __restrict__ xr, unsigned* __restrict__ mode) {
  __shared__ int zc, bg;
  int t = threadIdx.x;   // 256
  if (t == 0) { zc = 0; bg = 0; }
  __syncthreads();
  int zeros_even = 0; int big = 0;
  for (int i = t; i < 4096; i += 256) {
    u16 v = xr[i];
    if (!(i & 1) && v == 0) zeros_even++;
    if (fabsf(bf2f(v)) > 1e6f) big = 1;
  }
  atomicAdd(&zc, zeros_even);
  if (big) atomicOr(&bg, 1);
  __syncthreads();
  if (t == 0) *mode = (zc > 512 || bg) ? 1u : 0u;   // 1 = fp32 storage
}

// ---- adj storage detection (u32 pair pattern 0x00003F80 unique to bf16).
__global__ void detect_adj(const unsigned* __restrict__ a, unsigned* __restrict__ amode) {
  __shared__ int clo;
  int t = threadIdx.x;   // 256
  if (t == 0) clo = 0;
  __syncthreads();
  int c = 0;
  for (int i = t; i < 4096; i += 256)
    if (a[i] == 0x00003F80u) c++;
  atomicAdd(&clo, c);
  __syncthreads();
  if (t == 0) *amode = (clo > 32) ? 1u : 0u;   // 1 = bf16 storage
}

// ---- adjacency -> bitmask (8 MB). byte b covers elements [b*8, b*8+8),
// bit q = (elem b*8+q != 0). Fully coalesced read/write; one streaming pass.
__global__ __launch_bounds__(256) void adj_bits(const void* __restrict__ adj,
    unsigned char* __restrict__ bits, const unsigned* __restrict__ amodep) {
  int amode = (int)*amodep;
  for (size_t b = (size_t)blockIdx.x * 256 + threadIdx.x; b < 8388608; b += 524288) {
    size_t e0 = b * 8;
    unsigned byte = 0;
    if (amode == 0) {          // u32/f32 storage
      int4 a0 = *(const int4*)((const int*)adj + e0);
      int4 a1 = *(const int4*)((const int*)adj + e0 + 4);
      byte = (a0.x != 0) | ((a0.y != 0) << 1) | ((a0.z != 0) << 2) | ((a0.w != 0) << 3) |
             ((a1.x != 0) << 4) | ((a1.y != 0) << 5) | ((a1.z != 0) << 6) | ((a1.w != 0) << 7);
    } else {                   // bf16 storage
      ushort4 a0 = *(const ushort4*)((const u16*)adj + e0);
      ushort4 a1 = *(const ushort4*)((const u16*)adj + e0 + 4);
      byte = (a0.x != 0) | ((a0.y != 0) << 1) | ((a0.z != 0) << 2) | ((a0.w != 0) << 3) |
             ((a1.x != 0) << 4) | ((a1.y != 0) << 5) | ((a1.z != 0) << 6) | ((a1.w != 0) << 7);
    }
    bits[b] = (unsigned char)byte;
  }
}

// C[M x N] fp32 = Abf[M x K] @ BT[N x K]^T, all bf16 operands, MFMA, no LDS.
// grid (N/64, M/64), 256 threads; wave w owns rows w*16..+15, 4 n-tiles.
__global__ __launch_bounds__(256) void gemm_mfma(const u16* __restrict__ Abf,
    const u16* __restrict__ BT, float* __restrict__ C, int K, int N) {
  int tid = threadIdx.x;
  int l = tid & 63, w = tid >> 6;
  int m0 = blockIdx.y * 64, n0 = blockIdx.x * 64;
  const u16* arow = Abf + (size_t)(m0 + w * 16 + (l & 15)) * K + (l >> 4) * 8;
  const u16* brow = BT + (size_t)(n0 + (l & 15)) * K + (l >> 4) * 8;
  f32x4 acc[4];
#pragma unroll
  for (int nt = 0; nt < 4; ++nt) acc[nt] = (f32x4){0.f, 0.f, 0.f, 0.f};
  for (int k0 = 0; k0 < K; k0 += 32) {
    short8 a = *(const short8*)(arow + k0);
#pragma unroll
    for (int nt = 0; nt < 4; ++nt) {
      short8 b = *(const short8*)(brow + (size_t)nt * 16 * K + k0);
      acc[nt] = __builtin_amdgcn_mfma_f32_16x16x32_bf16(a, b, acc[nt], 0, 0, 0);
    }
  }
  // C/D layout: col = lane&15, row = (lane>>4)*4 + q
#pragma unroll
  for (int nt = 0; nt < 4; ++nt)
#pragma unroll
    for (int q = 0; q < 4; ++q)
      C[(size_t)(m0 + w * 16 + (l >> 4) * 4 + q) * N + n0 + nt * 16 + (l & 15)] =
          acc[nt][q];
}

// Layer-2/3 dual GEMM: C{0,1}[8192 x 64] fp32 = hbf[8192 x 256] @ BT{0,1}[64 x 256]^T.
__global__ __launch_bounds__(256) void gemm2_dual(const u16* __restrict__ Abf,
    const u16* __restrict__ BT0, const u16* __restrict__ BT1,
    float* __restrict__ C0, float* __restrict__ C1) {
  const int K = 256, N = 64;
  const u16* BT = blockIdx.x ? BT1 : BT0;
  float* C = blockIdx.x ? C1 : C0;
  int tid = threadIdx.x, l = tid & 63, w = tid >> 6;
  int m0 = blockIdx.y * 64;
  const u16* arow = Abf + (size_t)(m0 + w * 16 + (l & 15)) * K + (l >> 4) * 8;
  const u16* brow = BT + (size_t)(l & 15) * K + (l >> 4) * 8;
  f32x4 acc[4];
#pragma unroll
  for (int nt = 0; nt < 4; ++nt) acc[nt] = (f32x4){0.f, 0.f, 0.f, 0.f};
  for (int k0 = 0; k0 < K; k0 += 32) {
    short8 a = *(const short8*)(arow + k0);
#pragma unroll
    for (int nt = 0; nt < 4; ++nt) {
      short8 b = *(const short8*)(brow + (size_t)nt * 16 * K + k0);
      acc[nt] = __builtin_amdgcn_mfma_f32_16x16x32_bf16(a, b, acc[nt], 0, 0, 0);
    }
  }
#pragma unroll
  for (int nt = 0; nt < 4; ++nt)
#pragma unroll
    for (int q = 0; q < 4; ++q)
      C[(size_t)(m0 + w * 16 + (l >> 4) * 4 + q) * N + nt * 16 + (l & 15)] = acc[nt][q];
}

// bf16 copy of a mode-aware buffer (8 elems/thread). n8 = elems/8.
__global__ __launch_bounds__(256) void convert_bf16(const void* __restrict__ in,
    u16* __restrict__ out, int n8, const unsigned* __restrict__ modep) {
  int f32 = (int)*modep;
  int i = blockIdx.x * 256 + threadIdx.x;
  if (i >= n8) return;
  if (f32) {
    float4 v0 = ((const float4*)in)[(size_t)i * 2];
    float4 v1 = ((const float4*)in)[(size_t)i * 2 + 1];
    ushort4 o0 = {f2bf(v0.x), f2bf(v0.y), f2bf(v0.z), f2bf(v0.w)};
    ushort4 o1 = {f2bf(v1.x), f2bf(v1.y), f2bf(v1.z), f2bf(v1.w)};
    ((ushort4*)out)[(size_t)i * 2] = o0;
    ((ushort4*)out)[(size_t)i * 2 + 1] = o1;
  } else {
    ((int4*)out)[i] = ((const int4*)in)[i];   // already bf16: raw copy
  }
}

// transpose + bf16 convert: in fp32 [M][F] -> out bf16 [F][M]. grid (M/32, F/32).
__global__ __launch_bounds__(256) void transpose_bf16(const float* __restrict__ in,
    u16* __restrict__ out, int M, int F) {
  __shared__ float t[32][33];
  int m0 = blockIdx.x * 32, f0 = blockIdx.y * 32;
  int c = threadIdx.x & 31, r = threadIdx.x >> 5;   // r = 0..7
  for (int rr = r; rr < 32; rr += 8)
    t[rr][c] = in[(size_t)(m0 + rr) * F + f0 + c];
  __syncthreads();
  for (int rr = r; rr < 32; rr += 8)
    out[(size_t)(f0 + rr) * M + m0 + c] = f2bf(t[c][rr]);
}

// transpose + bf16 convert from a RAW (mode-aware) buffer. grid (M/32, F/32).
__global__ __launch_bounds__(256) void transpose_any(const void* __restrict__ in,
    u16* __restrict__ out, int M, int F, const unsigned* __restrict__ modep) {
  int f32 = (int)*modep;
  __shared__ u16 t[32][33];
  int m0 = blockIdx.x * 32, f0 = blockIdx.y * 32;
  int c = threadIdx.x & 31, r = threadIdx.x >> 5;
  for (int rr = r; rr < 32; rr += 8)
    t[rr][c] = f2bf(ldf(in, (size_t)(m0 + rr) * F + f0 + c, f32));
  __syncthreads();
  for (int rr = r; rr < 32; rr += 8)
    out[(size_t)(f0 + rr) * M + m0 + c] = t[c][rr];
}

// dual raw transpose (Wmu/Wlv -> WmuT/WlvT). grid (M/32, F/32, 2).
__global__ __launch_bounds__(256) void transpose_w2(const void* __restrict__ in0,
    const void* __restrict__ in1, u16* __restrict__ out0, u16* __restrict__ out1,
    int M, int F, const unsigned* __restrict__ modep) {
  int f32 = (int)*modep;
  const void* in = blockIdx.z ? in1 : in0;
  u16* out = blockIdx.z ? out1 : out0;
  __shared__ u16 t[32][33];
  int m0 = blockIdx.x * 32, f0 = blockIdx.y * 32;
  int c = threadIdx.x & 31, r = threadIdx.x >> 5;
  for (int rr = r; rr < 32; rr += 8)
    t[rr][c] = f2bf(ldf(in, (size_t)(m0 + rr) * F + f0 + c, f32));
  __syncthreads();
  for (int rr = r; rr < 32; rr += 8)
    out[(size_t)(f0 + rr) * M + m0 + c] = t[c][rr];
}

// dual fp32->bf16 transpose (whmu/whlv -> whmuT/whlvT). grid (M/32, F/32, 2).
__global__ __launch_bounds__(256) void transpose_pair(const float* __restrict__ in0,
    const float* __restrict__ in1, u16* __restrict__ out0, u16* __restrict__ out1,
    int M, int F) {
  const float* in = blockIdx.z ? in1 : in0;
  u16* out = blockIdx.z ? out1 : out0;
  __shared__ float t[32][33];
  int m0 = blockIdx.x * 32, f0 = blockIdx.y * 32;
  int c = threadIdx.x & 31, r = threadIdx.x >> 5;
  for (int rr = r; rr < 32; rr += 8)
    t[rr][c] = in[(size_t)(m0 + rr) * F + f0 + c];
  __syncthreads();
  for (int rr = r; rr < 32; rr += 8)
    out[(size_t)(f0 + rr) * M + m0 + c] = f2bf(t[c][rr]);
}

// s_i = Wh_i . a[:F], d_i = Wh_i . a[F:] (Wh fp32, a raw). NO atomics.
__global__ __launch_bounds__(256) void sd_f32(const float* __restrict__ Wh,
    const void* __restrict__ a2, float* __restrict__ s, float* __restrict__ d,
    int F, const unsigned* __restrict__ modep) {
  int f32 = (int)*modep;
  int row = blockIdx.x * 4 + (threadIdx.x >> 6);
  int l = threadIdx.x & 63;
  float ss = 0.f, dd = 0.f;
  for (int k = l; k < F; k += 64) {
    float wv = Wh[(size_t)row * F + k];
    ss += wv * ldf(a2, k, f32);
    dd += wv * ldf(a2, F + k, f32);
  }
#pragma unroll
  for (int off = 32; off > 0; off >>= 1) {
    ss += __shfl_down(ss, off, 64);
    dd += __shfl_down(dd, off, 64);
  }
  if (l == 0) { s[row] = ss; d[row] = dd; }
}

// dual s/d for layers 2/3 (F = 64). grid (2048, 2). NO atomics.
__global__ __launch_bounds__(256) void sd_dual(const float* __restrict__ Wh0,
    const float* __restrict__ Wh1, const void* __restrict__ a0,
    const void* __restrict__ a1, float* __restrict__ s0, float* __restrict__ s1,
    float* __restrict__ d0, float* __restrict__ d1,
    const unsigned* __restrict__ modep) {
  int f32 = (int)*modep;
  int L = blockIdx.y;
  const float* Wh = L ? Wh1 : Wh0;
  const void* a2 = L ? a1 : a0;
  int row = blockIdx.x * 4 + (threadIdx.x >> 6);
  int l = threadIdx.x & 63;
  float wv = Wh[(size_t)row * 64 + l];
  float ss = wv * ldf(a2, l, f32);
  float dd = wv * ldf(a2, 64 + l, f32);
#pragma unroll
  for (int off = 32; off > 0; off >>= 1) {
    ss += __shfl_down(ss, off, 64);
    dd += __shfl_down(dd, off, 64);
  }
  if (l == 0) { (L ? s1 : s0)[row] = ss; (L ? d1 : d0)[row] = dd; }
}

// Dmax: single block per array, LDS tree, plain store. grid = #arrays.
__global__ __launch_bounds__(256) void dmax_reduce(const float* __restrict__ da,
    const float* __restrict__ db, float* __restrict__ cells) {
  const float* d = blockIdx.x ? db : da;
  __shared__ float red[256];
  float m = -3.4e38f;
  for (int i = threadIdx.x; i < NROW; i += 256) m = fmaxf(m, d[i]);
  red[threadIdx.x] = m;
  __syncthreads();
#pragma unroll
  for (int sft = 128; sft > 0; sft >>= 1) {
    if (threadIdx.x < sft) red[threadIdx.x] = fmaxf(red[threadIdx.x], red[threadIdx.x + sft]);
    __syncthreads();
  }
  if (threadIdx.x == 0) cells[blockIdx.x * 16] = red[0];
}

// Flash GAT v2 — wave-autonomous, BARRIER-FREE main loop.
// Each block owns 32 output rows; each WAVE owns a j-slice and computes its
// MFMA A-fragments (P values) DIRECTLY IN REGISTERS. No LDS P buffer, no
// per-iteration barriers. Partial O accumulated per wave over ALL n-tiles;
// one LDS cross-wave reduction at the end (reusing the dead dd_ buffer).
// NOTE (rule #20): EVERY access to acc[][] must be compile-time-indexed —
// the epilogue loops are fully #pragma unroll'd, else acc goes to scratch
// (round-9 regression: WRITE_SIZE 238 MB of spill traffic).
// NL=1 (FDIM=256): 8 waves x 1024-j slices, acc[2][16] (128 VGPR).
// NL=2 (FDIM=64): waves 0-3 layer a, 4-7 layer b, 2048-j slices, acc[2][4].
template <int NL>
__global__ __launch_bounds__(512, 2) void flash_v2(
    const u16* __restrict__ whTa, const u16* __restrict__ whTb,   // bf16 [FDIM][NROW]
    const float* __restrict__ sa, const float* __restrict__ da,
    const float* __restrict__ sb, const float* __restrict__ db,
    const float* __restrict__ cella, const float* __restrict__ cellb,
    const unsigned char* __restrict__ abits,
    void* __restrict__ o0, void* __restrict__ o1,
    void* __restrict__ o2, void* __restrict__ o3) {
  constexpr int FDIM = (NL == 1) ? 256 : 64;
  constexpr int NT = FDIM / 16;              // n-tiles per wave (all of them)
  constexpr int NW_L = (NL == 1) ? 8 : 4;    // waves per layer
  constexpr int JSL = NROW / NW_L;           // j-slice per wave
  constexpr int NKS = JSL / 32;              // MFMA k-steps per wave
  __shared__ __align__(16) float dd_[NL][NROW];   // d_j; reused as reduce buf
  __shared__ float lsp[8][32];
  __shared__ float ls_[NL][32];
  int tid = threadIdx.x, l = tid & 63, w = tid >> 6;
  int r0 = blockIdx.x * 32;
  int layer = (NL == 1) ? 0 : (w >> 2);
  int wl = (NL == 1) ? w : (w & 3);
  // stage d_j (float4 coalesced)
  for (int u = tid; u < NL * (NROW / 4); u += 512) {
    int L = u / (NROW / 4), uu = u - L * (NROW / 4);
    ((float4*)dd_[L])[uu] = ((const float4*)(L ? db : da))[uu];
  }
  __syncthreads();
  const u16* whT = layer ? whTb : whTa;
  const float* sW = layer ? sb : sa;
  const float* ddp = dd_[layer];
  float Dm = layer ? *cellb : *cella;
  int rlo = r0 + (l & 15);
  float sv0 = sW[rlo], sv1 = sW[rlo + 16];
  float t0 = sv0 + Dm, t1 = sv1 + Dm;
  float Ms0 = fmaxf(t0, 0.2f * t0), Ms1 = fmaxf(t1, 0.2f * t1);
  int jsbase = wl * JSL;
  int koff = (l >> 4) * 8;
  // adjacency bitmask: 16B covers 4 k-steps (byte kk*4 + (l>>4))
  const uint4* pb0 = (const uint4*)(abits + (size_t)rlo * 1024 + (jsbase >> 3));
  const uint4* pb1 = (const uint4*)(abits + (size_t)(rlo + 16) * 1024 + (jsbase >> 3));
  f32x4 acc[2][NT];
#pragma unroll
  for (int m = 0; m < 2; ++m)
#pragma unroll
    for (int n = 0; n < NT; ++n) acc[m][n] = (f32x4){0.f, 0.f, 0.f, 0.f};
  float psum0 = 0.f, psum1 = 0.f;
  int bsh = (l >> 4) * 8;                    // byte-in-word shift
  uint4 aw0 = pb0[0], aw1 = pb1[0];
  for (int g = 0; g < NKS / 4; ++g) {
    uint4 c0 = aw0, c1 = aw1;
    if (g + 1 < NKS / 4) { aw0 = pb0[g + 1]; aw1 = pb1[g + 1]; }
    unsigned wd0[4] = {c0.x, c0.y, c0.z, c0.w};
    unsigned wd1[4] = {c1.x, c1.y, c1.z, c1.w};
#pragma unroll
    for (int kk = 0; kk < 4; ++kk) {
      int j0 = jsbase + (g * 4 + kk) * 32;
      unsigned ab0 = (wd0[kk] >> bsh) & 0xffu;
      unsigned ab1 = (wd1[kk] >> bsh) & 0xffu;
      float4 dv0 = *(const float4*)&ddp[j0 + koff];
      float4 dv1 = *(const float4*)&ddp[j0 + koff + 4];
      float dvv[8] = {dv0.x, dv0.y, dv0.z, dv0.w, dv1.x, dv1.y, dv1.z, dv1.w};
      short8 af0, af1;
#pragma unroll
      for (int q = 0; q < 8; ++q) {
        float a0 = sv0 + dvv[q];
        float e0 = fmaxf(a0, 0.2f * a0) - Ms0;
        float p0 = ((ab0 >> q) & 1u) ? __expf(e0) : 0.f;
        psum0 += p0;
        af0[q] = (short)f2bf(p0);
        float a1 = sv1 + dvv[q];
        float e1 = fmaxf(a1, 0.2f * a1) - Ms1;
        float p1 = ((ab1 >> q) & 1u) ? __expf(e1) : 0.f;
        psum1 += p1;
        af1[q] = (short)f2bf(p1);
      }
      size_t jc = (size_t)(j0 + koff);
#pragma unroll
      for (int nt = 0; nt < NT; ++nt) {
        short8 b = *(const short8*)&whT[(size_t)(nt * 16 + (l & 15)) * NROW + jc];
        acc[0][nt] = __builtin_amdgcn_mfma_f32_16x16x32_bf16(af0, b, acc[0][nt], 0, 0, 0);
        acc[1][nt] = __builtin_amdgcn_mfma_f32_16x16x32_bf16(af1, b, acc[1][nt], 0, 0, 0);
      }
    }
  }
  // ---- lsum: wave shuffle-reduce (lanes sharing l&15) -> LDS -> sum waves
  psum0 += __shfl_xor(psum0, 16, 64); psum0 += __shfl_xor(psum0, 32, 64);
  psum1 += __shfl_xor(psum1, 16, 64); psum1 += __shfl_xor(psum1, 32, 64);
  if (l < 16) { lsp[w][l] = psum0; lsp[w][16 + l] = psum1; }
  __syncthreads();                    // also: all waves done with dd_ reads
  if (tid < 32 * NL) {
    int L = tid >> 5, r = tid & 31;
    float t = 0.f;
#pragma unroll
    for (int wv = 0; wv < NW_L; ++wv) t += lsp[L * NW_L + wv][r];
    ls_[L][r] = t;
  }
  __syncthreads();
  // ---- cross-wave O reduction (reuse dd_ as fp32 buffer)
  float* red = (float*)dd_;
  if constexpr (NL == 1) {
    u16* hb = (u16*)o0;
#pragma unroll
    for (int cg = 0; cg < 8; ++cg) {    // UNROLLED: acc index compile-time
#pragma unroll
      for (int mh = 0; mh < 2; ++mh)
#pragma unroll
        for (int ntl = 0; ntl < 2; ++ntl)
#pragma unroll
          for (int q = 0; q < 4; ++q)
            red[w * 1024 + (mh * 16 + (l >> 4) * 4 + q) * 32 + ntl * 16 + (l & 15)] =
                acc[mh][cg * 2 + ntl][q];
      __syncthreads();
      for (int e = tid; e < 1024; e += 512) {
        int r = e >> 5, c = e & 31;
        float x = 0.f;
#pragma unroll
        for (int wv = 0; wv < 8; ++wv) x += red[wv * 1024 + r * 32 + c];
        x /= ls_[0][r];
        x = (x > 0.f) ? x : (__expf(x) - 1.f);
        hb[(size_t)(r0 + r) * 256 + cg * 32 + c] = f2bf(x);
      }
      __syncthreads();
    }
  } else {
    // red layout: [L][wl][32 rows][64 cols] fp32 = 2 x 32KB (fits dd_)
#pragma unroll
    for (int mh = 0; mh < 2; ++mh)
#pragma unroll
      for (int nt = 0; nt < 4; ++nt)
#pragma unroll
        for (int q = 0; q < 4; ++q)
          red[layer * 8192 + wl * 2048 + (mh * 16 + (l >> 4) * 4 + q) * 64 +
              nt * 16 + (l & 15)] = acc[mh][nt][q];
    __syncthreads();
    for (int e = tid; e < 4096; e += 512) {
      int L = e >> 11, rc = e & 2047, r = rc >> 6, c = rc & 63;
      float x = 0.f;
#pragma unroll
      for (int wv = 0; wv < 4; ++wv) x += red[L * 8192 + wv * 2048 + r * 64 + c];
      x /= ls_[L][r];
      size_t gi = (size_t)(r0 + r) * 64 + c;
      ((float*)(L ? o2 : o0))[gi] = x;
      ((float*)(L ? o3 : o1))[gi] = x;
    }
  }
}

// logits = (mu + eps*exp(0.5*logvar)) @ Wc + bc. 256 blocks x 32 rows.
__global__ __launch_bounds__(256) void logits_f32(const float* __restrict__ mu,
    const float* __restrict__ lv, const void* __restrict__ eps,
    const void* __restrict__ Wc, const void* __restrict__ bcv,
    float* __restrict__ outL, const unsigned* __restrict__ modep) {
  int f32 = (int)*modep;
  __shared__ float zs[32 * 64];
  __shared__ float wcs[64 * 16];
  int tid = threadIdx.x;
  for (int i = tid; i < 1024; i += 256) wcs[i] = ldf(Wc, i, f32);
  int row0 = blockIdx.x * 32;
  for (int i = tid; i < 2048; i += 256) {
    int r = i >> 6, c = i & 63;
    size_t g = (size_t)(row0 + r) * 64 + c;
    zs[i] = mu[g] + ldf(eps, g, f32) * __expf(0.5f * lv[g]);
  }
  __syncthreads();
  for (int it = tid; it < 512; it += 256) {
    int r = it >> 4, oc = it & 15;
    float a = ldf(bcv, oc, f32);
    for (int c = 0; c < 64; ++c) a += zs[r * 64 + c] * wcs[c * 16 + oc];
    outL[(size_t)(row0 + r) * 16 + oc] = a;
  }
}

extern "C" void kernel_launch(void* const* d_in, const int* in_sizes, int n_in,
                              void* d_out, int out_size, void* d_ws, size_t ws_size,
                              hipStream_t stream) {
  (void)out_size; (void)ws_size;
  // ---- size-based input resolution (robust to permutation; ties in dict order)
  int ix = 0, iadj = 1, ieps = 2, iW1 = 3, ia1 = 4, iWmu = 5, iamu = 6,
      iWlv = 7, ialv = 8, iWc = 9, ibc = 10;
  {
    int fmu = -1, flv = -1, fam = -1, fal = -1;
    for (int i = 0; i < n_in; ++i) {
      switch (in_sizes[i]) {
        case 67108864: iadj = i; break;
        case 4194304:  ix   = i; break;
        case 524288:   ieps = i; break;
        case 131072:   iW1  = i; break;
        case 512:      ia1  = i; break;
        case 1024:     iWc  = i; break;
        case 16:       ibc  = i; break;
        case 16384:    if (fmu < 0) fmu = i; else flv = i; break;
        case 128:      if (fam < 0) fam = i; else fal = i; break;
        default: break;
      }
    }
    if (fmu >= 0 && flv >= 0) { iWmu = fmu; iWlv = flv; }
    if (fam >= 0 && fal >= 0) { iamu = fam; ialv = fal; }
  }
  const void* adj = d_in[iadj];
  char* ws = (char*)d_ws;
  const size_t KB = 1024, MB = 1024 * 1024;
  // ---- workspace (<= 33 MB) ----
  float* wh1   = (float*)(ws + 0);                 // 8MB [dead after sd1/transpose1]
  float* whmu  = (float*)(ws + 0);                 // 2MB [overlay]
  float* whlv  = (float*)(ws + 2 * MB);            // 2MB [overlay]
  float* muf   = (float*)(ws + 4 * MB);            // 2MB [overlay]
  float* lvf   = (float*)(ws + 6 * MB);            // 2MB [overlay]
  u16*   xbf   = (u16*)(ws + 8 * MB);              // 8MB bf16 x [dead after gemm1]
  u16*   whT1  = (u16*)(ws + 8 * MB);              // 4MB bf16 [256][8192] [overlay]
  u16*   hbf   = (u16*)(ws + 12 * MB);             // 4MB bf16 [8192][256]
  u16*   whmuT = (u16*)(ws + 20 * MB);             // 1MB bf16 [64][8192]
  u16*   whlvT = (u16*)(ws + 21 * MB);             // 1MB bf16 [64][8192]
  u16*   W1T   = (u16*)(ws + 22 * MB);             // 256KB bf16 [256][512]
  u16*   WmuT  = (u16*)(ws + 22 * MB + 256 * KB);  // 32KB bf16 [64][256]
  u16*   WlvT  = (u16*)(ws + 22 * MB + 288 * KB);  // 32KB bf16 [64][256]
  float* s1    = (float*)(ws + 24 * MB + 96 * KB);
  float* d1    = (float*)(ws + 24 * MB + 128 * KB);
  float* smu   = (float*)(ws + 24 * MB + 160 * KB);
  float* dmu   = (float*)(ws + 24 * MB + 192 * KB);
  float* slv   = (float*)(ws + 24 * MB + 224 * KB);
  float* dlv   = (float*)(ws + 24 * MB + 256 * KB);
  float* dmaxv = (float*)(ws + 24 * MB + 288 * KB);  // 3 cells, 64B apart
  unsigned* mode  = (unsigned*)(ws + 24 * MB + 289 * KB);
  unsigned* amode = (unsigned*)(ws + 24 * MB + 290 * KB);
  unsigned char* abits = (unsigned char*)(ws + 25 * MB);  // 8MB bitmask

  // fp32 output layout: [logits 8192*16 | mu 8192*64 | logvar 8192*64]
  float* out_logits = (float*)d_out;
  float* out_mu     = (float*)d_out + 131072;
  float* out_lv     = (float*)d_out + 655360;

  detect3<<<1, 256, 0, stream>>>((const u16*)d_in[ix], mode);
  detect_adj<<<1, 256, 0, stream>>>((const unsigned*)adj, amode);
  adj_bits<<<2048, 256, 0, stream>>>(adj, abits, amode);

  // layer 1: xbf/W1T bf16, Wh1 = xbf @ W1T^T (MFMA), WhT1 bf16, s/d + dmax,
  // barrier-free flash_v2 (256 blocks x 512 thr, fused elu->hbf)
  convert_bf16<<<2048, 256, 0, stream>>>(d_in[ix], xbf, 524288, mode);
  transpose_any<<<dim3(16, 8), 256, 0, stream>>>(d_in[iW1], W1T, 512, 256, mode);
  gemm_mfma<<<dim3(4, 128), 256, 0, stream>>>(xbf, W1T, wh1, 512, 256);
  transpose_bf16<<<dim3(256, 8), 256, 0, stream>>>(wh1, whT1, 8192, 256);
  sd_f32<<<2048, 256, 0, stream>>>(wh1, d_in[ia1], s1, d1, 256, mode);
  dmax_reduce<<<1, 256, 0, stream>>>(d1, d1, dmaxv + 0);
  flash_v2<1><<<256, 512, 0, stream>>>(whT1, nullptr, s1, d1,
      nullptr, nullptr, dmaxv + 0, nullptr, abits,
      hbf, nullptr, nullptr, nullptr);

  // layers 2/3: dual MFMA GEMM from hbf, dual transposes, dual s/d + dmax,
  // FUSED barrier-free flash_v2 (fused div + dual store)
  transpose_w2<<<dim3(8, 2, 2), 256, 0, stream>>>(d_in[iWmu], d_in[iWlv],
      WmuT, WlvT, 256, 64, mode);
  gemm2_dual<<<dim3(2, 128), 256, 0, stream>>>(hbf, WmuT, WlvT, whmu, whlv);
  transpose_pair<<<dim3(256, 2, 2), 256, 0, stream>>>(whmu, whlv, whmuT, whlvT,
      8192, 64);
  sd_dual<<<dim3(2048, 2), 256, 0, stream>>>(whmu, whlv, d_in[iamu], d_in[ialv],
      smu, slv, dmu, dlv, mode);
  dmax_reduce<<<2, 256, 0, stream>>>(dmu, dlv, dmaxv + 16);
  flash_v2<2><<<256, 512, 0, stream>>>(whmuT, whlvT, smu, dmu, slv, dlv,
      dmaxv + 16, dmaxv + 32, abits,
      muf, out_mu, lvf, out_lv);

  logits_f32<<<256, 256, 0, stream>>>(muf, lvf, d_in[ieps], d_in[iWc], d_in[ibc], out_logits, mode);
}

// Round 11
// 692.375 us; speedup vs baseline: 1.0943x; 1.0943x over previous
//
#include <hip/hip_runtime.h>

typedef unsigned short u16;
typedef __attribute__((ext_vector_type(8))) short short8;
typedef __attribute__((ext_vector_type(4))) float f32x4;

#define NROW 8192

__device__ __forceinline__ float bf2f(u16 h) {
  unsigned u = ((unsigned)h) << 16;
  return __builtin_bit_cast(float, u);
}
// mode-aware load: f32 ? fp32 storage : bf16 storage (upcast)
__device__ __forceinline__ float ldf(const void* p, size_t i, int f32) {
  return f32 ? ((const float*)p)[i] : bf2f(((const u16*)p)[i]);
}
// fp32 -> bf16 round-to-nearest-even
__device__ __forceinline__ u16 f2bf(float f) {
  unsigned b = __builtin_bit_cast(unsigned, f);
  b += 0x7FFFu + ((b >> 16) & 1u);
  return (u16)(b >> 16);
}

// ---- storage-dtype detection on x (N(0,1)).
__global__ void detect3(const u16* __restrict__ xr, unsigned* __restrict__ mode) {
  __shared__ int zc, bg;
  int t = threadIdx.x;   // 256
  if (t == 0) { zc = 0; bg = 0; }
  __syncthreads();
  int zeros_even = 0; int big = 0;
  for (int i = t; i < 4096; i += 256) {
    u16 v = xr[i];
    if (!(i & 1) && v == 0) zeros_even++;
    if (fabsf(bf2f(v)) > 1e6f) big = 1;
  }
  atomicAdd(&zc, zeros_even);
  if (big) atomicOr(&bg, 1);
  __syncthreads();
  if (t == 0) *mode = (zc > 512 || bg) ? 1u : 0u;   // 1 = fp32 storage
}

// ---- adj storage detection (u32 pair pattern 0x00003F80 unique to bf16).
__global__ void detect_adj(const unsigned* __restrict__ a, unsigned* __restrict__ amode) {
  __shared__ int clo;
  int t = threadIdx.x;   // 256
  if (t == 0) clo = 0;
  __syncthreads();
  int c = 0;
  for (int i = t; i < 4096; i += 256)
    if (a[i] == 0x00003F80u) c++;
  atomicAdd(&clo, c);
  __syncthreads();
  if (t == 0) *amode = (clo > 32) ? 1u : 0u;   // 1 = bf16 storage
}

// ---- adjacency -> bitmask (8 MB). byte b covers elements [b*8, b*8+8),
// bit q = (elem b*8+q != 0). Fully coalesced read/write; one streaming pass.
__global__ __launch_bounds__(256) void adj_bits(const void* __restrict__ adj,
    unsigned char* __restrict__ bits, const unsigned* __restrict__ amodep) {
  int amode = (int)*amodep;
  for (size_t b = (size_t)blockIdx.x * 256 + threadIdx.x; b < 8388608; b += 524288) {
    size_t e0 = b * 8;
    unsigned byte = 0;
    if (amode == 0) {          // u32/f32 storage
      int4 a0 = *(const int4*)((const int*)adj + e0);
      int4 a1 = *(const int4*)((const int*)adj + e0 + 4);
      byte = (a0.x != 0) | ((a0.y != 0) << 1) | ((a0.z != 0) << 2) | ((a0.w != 0) << 3) |
             ((a1.x != 0) << 4) | ((a1.y != 0) << 5) | ((a1.z != 0) << 6) | ((a1.w != 0) << 7);
    } else {                   // bf16 storage
      ushort4 a0 = *(const ushort4*)((const u16*)adj + e0);
      ushort4 a1 = *(const ushort4*)((const u16*)adj + e0 + 4);
      byte = (a0.x != 0) | ((a0.y != 0) << 1) | ((a0.z != 0) << 2) | ((a0.w != 0) << 3) |
             ((a1.x != 0) << 4) | ((a1.y != 0) << 5) | ((a1.z != 0) << 6) | ((a1.w != 0) << 7);
    }
    bits[b] = (unsigned char)byte;
  }
}

// C[M x N] fp32 = Abf[M x K] @ BT[N x K]^T, all bf16 operands, MFMA, no LDS.
// grid (N/64, M/64), 256 threads; wave w owns rows w*16..+15, 4 n-tiles.
__global__ __launch_bounds__(256) void gemm_mfma(const u16* __restrict__ Abf,
    const u16* __restrict__ BT, float* __restrict__ C, int K, int N) {
  int tid = threadIdx.x;
  int l = tid & 63, w = tid >> 6;
  int m0 = blockIdx.y * 64, n0 = blockIdx.x * 64;
  const u16* arow = Abf + (size_t)(m0 + w * 16 + (l & 15)) * K + (l >> 4) * 8;
  const u16* brow = BT + (size_t)(n0 + (l & 15)) * K + (l >> 4) * 8;
  f32x4 acc[4];
#pragma unroll
  for (int nt = 0; nt < 4; ++nt) acc[nt] = (f32x4){0.f, 0.f, 0.f, 0.f};
  for (int k0 = 0; k0 < K; k0 += 32) {
    short8 a = *(const short8*)(arow + k0);
#pragma unroll
    for (int nt = 0; nt < 4; ++nt) {
      short8 b = *(const short8*)(brow + (size_t)nt * 16 * K + k0);
      acc[nt] = __builtin_amdgcn_mfma_f32_16x16x32_bf16(a, b, acc[nt], 0, 0, 0);
    }
  }
  // C/D layout: col = lane&15, row = (lane>>4)*4 + q
#pragma unroll
  for (int nt = 0; nt < 4; ++nt)
#pragma unroll
    for (int q = 0; q < 4; ++q)
      C[(size_t)(m0 + w * 16 + (l >> 4) * 4 + q) * N + n0 + nt * 16 + (l & 15)] =
          acc[nt][q];
}

// Layer-2/3 dual GEMM: C{0,1}[8192 x 64] fp32 = hbf[8192 x 256] @ BT{0,1}[64 x 256]^T.
__global__ __launch_bounds__(256) void gemm2_dual(const u16* __restrict__ Abf,
    const u16* __restrict__ BT0, const u16* __restrict__ BT1,
    float* __restrict__ C0, float* __restrict__ C1) {
  const int K = 256, N = 64;
  const u16* BT = blockIdx.x ? BT1 : BT0;
  float* C = blockIdx.x ? C1 : C0;
  int tid = threadIdx.x, l = tid & 63, w = tid >> 6;
  int m0 = blockIdx.y * 64;
  const u16* arow = Abf + (size_t)(m0 + w * 16 + (l & 15)) * K + (l >> 4) * 8;
  const u16* brow = BT + (size_t)(l & 15) * K + (l >> 4) * 8;
  f32x4 acc[4];
#pragma unroll
  for (int nt = 0; nt < 4; ++nt) acc[nt] = (f32x4){0.f, 0.f, 0.f, 0.f};
  for (int k0 = 0; k0 < K; k0 += 32) {
    short8 a = *(const short8*)(arow + k0);
#pragma unroll
    for (int nt = 0; nt < 4; ++nt) {
      short8 b = *(const short8*)(brow + (size_t)nt * 16 * K + k0);
      acc[nt] = __builtin_amdgcn_mfma_f32_16x16x32_bf16(a, b, acc[nt], 0, 0, 0);
    }
  }
#pragma unroll
  for (int nt = 0; nt < 4; ++nt)
#pragma unroll
    for (int q = 0; q < 4; ++q)
      C[(size_t)(m0 + w * 16 + (l >> 4) * 4 + q) * N + nt * 16 + (l & 15)] = acc[nt][q];
}

// bf16 copy of a mode-aware buffer (8 elems/thread). n8 = elems/8.
__global__ __launch_bounds__(256) void convert_bf16(const void* __restrict__ in,
    u16* __restrict__ out, int n8, const unsigned* __restrict__ modep) {
  int f32 = (int)*modep;
  int i = blockIdx.x * 256 + threadIdx.x;
  if (i >= n8) return;
  if (f32) {
    float4 v0 = ((const float4*)in)[(size_t)i * 2];
    float4 v1 = ((const float4*)in)[(size_t)i * 2 + 1];
    ushort4 o0 = {f2bf(v0.x), f2bf(v0.y), f2bf(v0.z), f2bf(v0.w)};
    ushort4 o1 = {f2bf(v1.x), f2bf(v1.y), f2bf(v1.z), f2bf(v1.w)};
    ((ushort4*)out)[(size_t)i * 2] = o0;
    ((ushort4*)out)[(size_t)i * 2 + 1] = o1;
  } else {
    ((int4*)out)[i] = ((const int4*)in)[i];   // already bf16: raw copy
  }
}

// transpose + bf16 convert: in fp32 [M][F] -> out bf16 [F][M]. grid (M/32, F/32).
__global__ __launch_bounds__(256) void transpose_bf16(const float* __restrict__ in,
    u16* __restrict__ out, int M, int F) {
  __shared__ float t[32][33];
  int m0 = blockIdx.x * 32, f0 = blockIdx.y * 32;
  int c = threadIdx.x & 31, r = threadIdx.x >> 5;   // r = 0..7
  for (int rr = r; rr < 32; rr += 8)
    t[rr][c] = in[(size_t)(m0 + rr) * F + f0 + c];
  __syncthreads();
  for (int rr = r; rr < 32; rr += 8)
    out[(size_t)(f0 + rr) * M + m0 + c] = f2bf(t[c][rr]);
}

// transpose + bf16 convert from a RAW (mode-aware) buffer. grid (M/32, F/32).
__global__ __launch_bounds__(256) void transpose_any(const void* __restrict__ in,
    u16* __restrict__ out, int M, int F, const unsigned* __restrict__ modep) {
  int f32 = (int)*modep;
  __shared__ u16 t[32][33];
  int m0 = blockIdx.x * 32, f0 = blockIdx.y * 32;
  int c = threadIdx.x & 31, r = threadIdx.x >> 5;
  for (int rr = r; rr < 32; rr += 8)
    t[rr][c] = f2bf(ldf(in, (size_t)(m0 + rr) * F + f0 + c, f32));
  __syncthreads();
  for (int rr = r; rr < 32; rr += 8)
    out[(size_t)(f0 + rr) * M + m0 + c] = t[c][rr];
}

// dual raw transpose (Wmu/Wlv -> WmuT/WlvT). grid (M/32, F/32, 2).
__global__ __launch_bounds__(256) void transpose_w2(const void* __restrict__ in0,
    const void* __restrict__ in1, u16* __restrict__ out0, u16* __restrict__ out1,
    int M, int F, const unsigned* __restrict__ modep) {
  int f32 = (int)*modep;
  const void* in = blockIdx.z ? in1 : in0;
  u16* out = blockIdx.z ? out1 : out0;
  __shared__ u16 t[32][33];
  int m0 = blockIdx.x * 32, f0 = blockIdx.y * 32;
  int c = threadIdx.x & 31, r = threadIdx.x >> 5;
  for (int rr = r; rr < 32; rr += 8)
    t[rr][c] = f2bf(ldf(in, (size_t)(m0 + rr) * F + f0 + c, f32));
  __syncthreads();
  for (int rr = r; rr < 32; rr += 8)
    out[(size_t)(f0 + rr) * M + m0 + c] = t[c][rr];
}

// dual fp32->bf16 transpose (whmu/whlv -> whmuT/whlvT). grid (M/32, F/32, 2).
__global__ __launch_bounds__(256) void transpose_pair(const float* __restrict__ in0,
    const float* __restrict__ in1, u16* __restrict__ out0, u16* __restrict__ out1,
    int M, int F) {
  const float* in = blockIdx.z ? in1 : in0;
  u16* out = blockIdx.z ? out1 : out0;
  __shared__ float t[32][33];
  int m0 = blockIdx.x * 32, f0 = blockIdx.y * 32;
  int c = threadIdx.x & 31, r = threadIdx.x >> 5;
  for (int rr = r; rr < 32; rr += 8)
    t[rr][c] = in[(size_t)(m0 + rr) * F + f0 + c];
  __syncthreads();
  for (int rr = r; rr < 32; rr += 8)
    out[(size_t)(f0 + rr) * M + m0 + c] = f2bf(t[c][rr]);
}

// s_i = Wh_i . a[:F], d_i = Wh_i . a[F:] (Wh fp32, a raw). NO atomics.
__global__ __launch_bounds__(256) void sd_f32(const float* __restrict__ Wh,
    const void* __restrict__ a2, float* __restrict__ s, float* __restrict__ d,
    int F, const unsigned* __restrict__ modep) {
  int f32 = (int)*modep;
  int row = blockIdx.x * 4 + (threadIdx.x >> 6);
  int l = threadIdx.x & 63;
  float ss = 0.f, dd = 0.f;
  for (int k = l; k < F; k += 64) {
    float wv = Wh[(size_t)row * F + k];
    ss += wv * ldf(a2, k, f32);
    dd += wv * ldf(a2, F + k, f32);
  }
#pragma unroll
  for (int off = 32; off > 0; off >>= 1) {
    ss += __shfl_down(ss, off, 64);
    dd += __shfl_down(dd, off, 64);
  }
  if (l == 0) { s[row] = ss; d[row] = dd; }
}

// dual s/d for layers 2/3 (F = 64). grid (2048, 2). NO atomics.
__global__ __launch_bounds__(256) void sd_dual(const float* __restrict__ Wh0,
    const float* __restrict__ Wh1, const void* __restrict__ a0,
    const void* __restrict__ a1, float* __restrict__ s0, float* __restrict__ s1,
    float* __restrict__ d0, float* __restrict__ d1,
    const unsigned* __restrict__ modep) {
  int f32 = (int)*modep;
  int L = blockIdx.y;
  const float* Wh = L ? Wh1 : Wh0;
  const void* a2 = L ? a1 : a0;
  int row = blockIdx.x * 4 + (threadIdx.x >> 6);
  int l = threadIdx.x & 63;
  float wv = Wh[(size_t)row * 64 + l];
  float ss = wv * ldf(a2, l, f32);
  float dd = wv * ldf(a2, 64 + l, f32);
#pragma unroll
  for (int off = 32; off > 0; off >>= 1) {
    ss += __shfl_down(ss, off, 64);
    dd += __shfl_down(dd, off, 64);
  }
  if (l == 0) { (L ? s1 : s0)[row] = ss; (L ? d1 : d0)[row] = dd; }
}

// Dmax: single block per array, LDS tree, plain store. grid = #arrays.
__global__ __launch_bounds__(256) void dmax_reduce(const float* __restrict__ da,
    const float* __restrict__ db, float* __restrict__ cells) {
  const float* d = blockIdx.x ? db : da;
  __shared__ float red[256];
  float m = -3.4e38f;
  for (int i = threadIdx.x; i < NROW; i += 256) m = fmaxf(m, d[i]);
  red[threadIdx.x] = m;
  __syncthreads();
#pragma unroll
  for (int sft = 128; sft > 0; sft >>= 1) {
    if (threadIdx.x < sft) red[threadIdx.x] = fmaxf(red[threadIdx.x], red[threadIdx.x + sft]);
    __syncthreads();
  }
  if (threadIdx.x == 0) cells[blockIdx.x * 16] = red[0];
}

// Flash GAT v3 — wave-autonomous, barrier-free main loop, SPILL-FREE.
// Round-10 lesson: __launch_bounds__(512,2) capped VGPRs at 128 (2 blocks/CU)
// and forced the acc[2][16] accumulator into scratch (238 MB spill traffic).
// Fix: (1) __launch_bounds__(512,1) -> cap >= 256 VGPR; (2) nt-split the
// NL=1 mapping so acc is acc[2][8] = 64 VGPRs.
// Wave mapping (8 waves, j-slice JSL=2048, NKS=64 k-steps):
//   NL=1 (FDIM=256): nh = w>>2 (n-half: tiles nh*8..+7), js = w&3.
//     P for a j-slice is computed by BOTH nh waves (cheap VALU dup);
//     lsum written only by nh==0.
//   NL=2 (FDIM=64): layer = w>>2, js = w&3, all 4 n-tiles per wave.
// Epilogue: LDS cross-wave reduce (reuse dd_), fused normalize+activation.
template <int NL>
__global__ __launch_bounds__(512, 1) void flash_v3(
    const u16* __restrict__ whTa, const u16* __restrict__ whTb,   // bf16 [FDIM][NROW]
    const float* __restrict__ sa, const float* __restrict__ da,
    const float* __restrict__ sb, const float* __restrict__ db,
    const float* __restrict__ cella, const float* __restrict__ cellb,
    const unsigned char* __restrict__ abits,
    void* __restrict__ o0, void* __restrict__ o1,
    void* __restrict__ o2, void* __restrict__ o3) {
  constexpr int FDIM = (NL == 1) ? 256 : 64;
  constexpr int NT = (NL == 1) ? 8 : 4;      // n-tiles per wave
  constexpr int JSL = 2048;                  // j-slice per wave
  constexpr int NKS = JSL / 32;              // 64 k-steps per wave
  __shared__ __align__(16) float dd_[NL][NROW];   // d_j; reused as reduce buf
  __shared__ float lsp[8][32];
  __shared__ float ls_[NL][32];
  int tid = threadIdx.x, l = tid & 63, w = tid >> 6;
  int r0 = blockIdx.x * 32;
  int layer = (NL == 1) ? 0 : (w >> 2);
  int js = w & 3;
  int nh = (NL == 1) ? (w >> 2) : 0;
  int ntbase = nh * 8;
  // stage d_j (float4 coalesced)
  for (int u = tid; u < NL * (NROW / 4); u += 512) {
    int L = u / (NROW / 4), uu = u - L * (NROW / 4);
    ((float4*)dd_[L])[uu] = ((const float4*)(L ? db : da))[uu];
  }
  __syncthreads();
  const u16* whT = layer ? whTb : whTa;
  const float* sW = layer ? sb : sa;
  const float* ddp = dd_[layer];
  float Dm = layer ? *cellb : *cella;
  int rlo = r0 + (l & 15);
  float sv0 = sW[rlo], sv1 = sW[rlo + 16];
  float t0 = sv0 + Dm, t1 = sv1 + Dm;
  float Ms0 = fmaxf(t0, 0.2f * t0), Ms1 = fmaxf(t1, 0.2f * t1);
  int jsbase = js * JSL;
  int koff = (l >> 4) * 8;
  // adjacency bitmask: 16B covers 4 k-steps (byte kk*4 + (l>>4))
  const uint4* pb0 = (const uint4*)(abits + (size_t)rlo * 1024 + (jsbase >> 3));
  const uint4* pb1 = (const uint4*)(abits + (size_t)(rlo + 16) * 1024 + (jsbase >> 3));
  f32x4 acc[2][NT];                          // NL=1: 64 VGPR; NL=2: 32 VGPR
#pragma unroll
  for (int m = 0; m < 2; ++m)
#pragma unroll
    for (int n = 0; n < NT; ++n) acc[m][n] = (f32x4){0.f, 0.f, 0.f, 0.f};
  float psum0 = 0.f, psum1 = 0.f;
  int bsh = (l >> 4) * 8;                    // byte-in-word shift
  uint4 aw0 = pb0[0], aw1 = pb1[0];
  for (int g = 0; g < NKS / 4; ++g) {        // 16 iterations
    uint4 c0 = aw0, c1 = aw1;
    if (g + 1 < NKS / 4) { aw0 = pb0[g + 1]; aw1 = pb1[g + 1]; }
    unsigned wd0[4] = {c0.x, c0.y, c0.z, c0.w};
    unsigned wd1[4] = {c1.x, c1.y, c1.z, c1.w};
#pragma unroll
    for (int kk = 0; kk < 4; ++kk) {
      int j0 = jsbase + (g * 4 + kk) * 32;
      unsigned ab0 = (wd0[kk] >> bsh) & 0xffu;
      unsigned ab1 = (wd1[kk] >> bsh) & 0xffu;
      float4 dv0 = *(const float4*)&ddp[j0 + koff];
      float4 dv1 = *(const float4*)&ddp[j0 + koff + 4];
      float dvv[8] = {dv0.x, dv0.y, dv0.z, dv0.w, dv1.x, dv1.y, dv1.z, dv1.w};
      short8 af0, af1;
#pragma unroll
      for (int q = 0; q < 8; ++q) {
        float a0 = sv0 + dvv[q];
        float e0 = fmaxf(a0, 0.2f * a0) - Ms0;
        float p0 = ((ab0 >> q) & 1u) ? __expf(e0) : 0.f;
        psum0 += p0;
        af0[q] = (short)f2bf(p0);
        float a1 = sv1 + dvv[q];
        float e1 = fmaxf(a1, 0.2f * a1) - Ms1;
        float p1 = ((ab1 >> q) & 1u) ? __expf(e1) : 0.f;
        psum1 += p1;
        af1[q] = (short)f2bf(p1);
      }
      size_t jc = (size_t)(j0 + koff);
#pragma unroll
      for (int nt = 0; nt < NT; ++nt) {
        short8 b = *(const short8*)&whT[(size_t)((ntbase + nt) * 16 + (l & 15)) * NROW + jc];
        acc[0][nt] = __builtin_amdgcn_mfma_f32_16x16x32_bf16(af0, b, acc[0][nt], 0, 0, 0);
        acc[1][nt] = __builtin_amdgcn_mfma_f32_16x16x32_bf16(af1, b, acc[1][nt], 0, 0, 0);
      }
    }
  }
  // ---- lsum: wave shuffle-reduce (lanes sharing l&15) -> LDS -> sum 4 slices
  psum0 += __shfl_xor(psum0, 16, 64); psum0 += __shfl_xor(psum0, 32, 64);
  psum1 += __shfl_xor(psum1, 16, 64); psum1 += __shfl_xor(psum1, 32, 64);
  bool wlead = (NL == 1) ? (nh == 0) : true;     // avoid double count (NL=1)
  int lspi = (NL == 1) ? js : (layer * 4 + js);
  if (l < 16 && wlead) { lsp[lspi][l] = psum0; lsp[lspi][16 + l] = psum1; }
  __syncthreads();                    // also: all waves done with dd_ reads
  if (tid < 32 * NL) {
    int L = tid >> 5, r = tid & 31;
    float t = 0.f;
#pragma unroll
    for (int wv = 0; wv < 4; ++wv) t += lsp[L * 4 + wv][r];
    ls_[L][r] = t;
  }
  __syncthreads();
  // ---- cross-wave O reduction (reuse dd_ as fp32 buffer)
  float* red = (float*)dd_;
  if constexpr (NL == 1) {
    u16* hb = (u16*)o0;
    // red[nh][js][32 rows][32 cols] = 32 KB (fits dd_[1][8192])
#pragma unroll
    for (int cgl = 0; cgl < 4; ++cgl) {   // local 32-col group; acc idx static
#pragma unroll
      for (int mh = 0; mh < 2; ++mh)
#pragma unroll
        for (int ntl = 0; ntl < 2; ++ntl)
#pragma unroll
          for (int q = 0; q < 4; ++q)
            red[nh * 4096 + js * 1024 + (mh * 16 + (l >> 4) * 4 + q) * 32 +
                ntl * 16 + (l & 15)] = acc[mh][cgl * 2 + ntl][q];
      __syncthreads();
      for (int e = tid; e < 2048; e += 512) {
        int nh2 = e >> 10, rc = e & 1023, r = rc >> 5, c = rc & 31;
        float x = 0.f;
#pragma unroll
        for (int wv = 0; wv < 4; ++wv) x += red[nh2 * 4096 + wv * 1024 + r * 32 + c];
        x /= ls_[0][r];
        x = (x > 0.f) ? x : (__expf(x) - 1.f);
        hb[(size_t)(r0 + r) * 256 + nh2 * 128 + cgl * 32 + c] = f2bf(x);
      }
      __syncthreads();
    }
  } else {
    // red layout: [L][js][32 rows][64 cols] fp32 = 2 x 32KB (fits dd_)
#pragma unroll
    for (int mh = 0; mh < 2; ++mh)
#pragma unroll
      for (int nt = 0; nt < 4; ++nt)
#pragma unroll
        for (int q = 0; q < 4; ++q)
          red[layer * 8192 + js * 2048 + (mh * 16 + (l >> 4) * 4 + q) * 64 +
              nt * 16 + (l & 15)] = acc[mh][nt][q];
    __syncthreads();
    for (int e = tid; e < 4096; e += 512) {
      int L = e >> 11, rc = e & 2047, r = rc >> 6, c = rc & 63;
      float x = 0.f;
#pragma unroll
      for (int wv = 0; wv < 4; ++wv) x += red[L * 8192 + wv * 2048 + r * 64 + c];
      x /= ls_[L][r];
      size_t gi = (size_t)(r0 + r) * 64 + c;
      ((float*)(L ? o2 : o0))[gi] = x;
      ((float*)(L ? o3 : o1))[gi] = x;
    }
  }
}

// logits = (mu + eps*exp(0.5*logvar)) @ Wc + bc. 256 blocks x 32 rows.
__global__ __launch_bounds__(256) void logits_f32(const float* __restrict__ mu,
    const float* __restrict__ lv, const void* __restrict__ eps,
    const void* __restrict__ Wc, const void* __restrict__ bcv,
    float* __restrict__ outL, const unsigned* __restrict__ modep) {
  int f32 = (int)*modep;
  __shared__ float zs[32 * 64];
  __shared__ float wcs[64 * 16];
  int tid = threadIdx.x;
  for (int i = tid; i < 1024; i += 256) wcs[i] = ldf(Wc, i, f32);
  int row0 = blockIdx.x * 32;
  for (int i = tid; i < 2048; i += 256) {
    int r = i >> 6, c = i & 63;
    size_t g = (size_t)(row0 + r) * 64 + c;
    zs[i] = mu[g] + ldf(eps, g, f32) * __expf(0.5f * lv[g]);
  }
  __syncthreads();
  for (int it = tid; it < 512; it += 256) {
    int r = it >> 4, oc = it & 15;
    float a = ldf(bcv, oc, f32);
    for (int c = 0; c < 64; ++c) a += zs[r * 64 + c] * wcs[c * 16 + oc];
    outL[(size_t)(row0 + r) * 16 + oc] = a;
  }
}

extern "C" void kernel_launch(void* const* d_in, const int* in_sizes, int n_in,
                              void* d_out, int out_size, void* d_ws, size_t ws_size,
                              hipStream_t stream) {
  (void)out_size; (void)ws_size;
  // ---- size-based input resolution (robust to permutation; ties in dict order)
  int ix = 0, iadj = 1, ieps = 2, iW1 = 3, ia1 = 4, iWmu = 5, iamu = 6,
      iWlv = 7, ialv = 8, iWc = 9, ibc = 10;
  {
    int fmu = -1, flv = -1, fam = -1, fal = -1;
    for (int i = 0; i < n_in; ++i) {
      switch (in_sizes[i]) {
        case 67108864: iadj = i; break;
        case 4194304:  ix   = i; break;
        case 524288:   ieps = i; break;
        case 131072:   iW1  = i; break;
        case 512:      ia1  = i; break;
        case 1024:     iWc  = i; break;
        case 16:       ibc  = i; break;
        case 16384:    if (fmu < 0) fmu = i; else flv = i; break;
        case 128:      if (fam < 0) fam = i; else fal = i; break;
        default: break;
      }
    }
    if (fmu >= 0 && flv >= 0) { iWmu = fmu; iWlv = flv; }
    if (fam >= 0 && fal >= 0) { iamu = fam; ialv = fal; }
  }
  const void* adj = d_in[iadj];
  char* ws = (char*)d_ws;
  const size_t KB = 1024, MB = 1024 * 1024;
  // ---- workspace (<= 33 MB) ----
  float* wh1   = (float*)(ws + 0);                 // 8MB [dead after sd1/transpose1]
  float* whmu  = (float*)(ws + 0);                 // 2MB [overlay]
  float* whlv  = (float*)(ws + 2 * MB);            // 2MB [overlay]
  float* muf   = (float*)(ws + 4 * MB);            // 2MB [overlay]
  float* lvf   = (float*)(ws + 6 * MB);            // 2MB [overlay]
  u16*   xbf   = (u16*)(ws + 8 * MB);              // 8MB bf16 x [dead after gemm1]
  u16*   whT1  = (u16*)(ws + 8 * MB);              // 4MB bf16 [256][8192] [overlay]
  u16*   hbf   = (u16*)(ws + 12 * MB);             // 4MB bf16 [8192][256]
  u16*   whmuT = (u16*)(ws + 20 * MB);             // 1MB bf16 [64][8192]
  u16*   whlvT = (u16*)(ws + 21 * MB);             // 1MB bf16 [64][8192]
  u16*   W1T   = (u16*)(ws + 22 * MB);             // 256KB bf16 [256][512]
  u16*   WmuT  = (u16*)(ws + 22 * MB + 256 * KB);  // 32KB bf16 [64][256]
  u16*   WlvT  = (u16*)(ws + 22 * MB + 288 * KB);  // 32KB bf16 [64][256]
  float* s1    = (float*)(ws + 24 * MB + 96 * KB);
  float* d1    = (float*)(ws + 24 * MB + 128 * KB);
  float* smu   = (float*)(ws + 24 * MB + 160 * KB);
  float* dmu   = (float*)(ws + 24 * MB + 192 * KB);
  float* slv   = (float*)(ws + 24 * MB + 224 * KB);
  float* dlv   = (float*)(ws + 24 * MB + 256 * KB);
  float* dmaxv = (float*)(ws + 24 * MB + 288 * KB);  // 3 cells, 64B apart
  unsigned* mode  = (unsigned*)(ws + 24 * MB + 289 * KB);
  unsigned* amode = (unsigned*)(ws + 24 * MB + 290 * KB);
  unsigned char* abits = (unsigned char*)(ws + 25 * MB);  // 8MB bitmask

  // fp32 output layout: [logits 8192*16 | mu 8192*64 | logvar 8192*64]
  float* out_logits = (float*)d_out;
  float* out_mu     = (float*)d_out + 131072;
  float* out_lv     = (float*)d_out + 655360;

  detect3<<<1, 256, 0, stream>>>((const u16*)d_in[ix], mode);
  detect_adj<<<1, 256, 0, stream>>>((const unsigned*)adj, amode);
  adj_bits<<<2048, 256, 0, stream>>>(adj, abits, amode);

  // layer 1: xbf/W1T bf16, Wh1 = xbf @ W1T^T (MFMA), WhT1 bf16, s/d + dmax,
  // barrier-free flash_v3 (256 blocks x 512 thr, fused elu->hbf)
  convert_bf16<<<2048, 256, 0, stream>>>(d_in[ix], xbf, 524288, mode);
  transpose_any<<<dim3(16, 8), 256, 0, stream>>>(d_in[iW1], W1T, 512, 256, mode);
  gemm_mfma<<<dim3(4, 128), 256, 0, stream>>>(xbf, W1T, wh1, 512, 256);
  transpose_bf16<<<dim3(256, 8), 256, 0, stream>>>(wh1, whT1, 8192, 256);
  sd_f32<<<2048, 256, 0, stream>>>(wh1, d_in[ia1], s1, d1, 256, mode);
  dmax_reduce<<<1, 256, 0, stream>>>(d1, d1, dmaxv + 0);
  flash_v3<1><<<256, 512, 0, stream>>>(whT1, nullptr, s1, d1,
      nullptr, nullptr, dmaxv + 0, nullptr, abits,
      hbf, nullptr, nullptr, nullptr);

  // layers 2/3: dual MFMA GEMM from hbf, dual transposes, dual s/d + dmax,
  // FUSED barrier-free flash_v3 (fused div + dual store)
  transpose_w2<<<dim3(8, 2, 2), 256, 0, stream>>>(d_in[iWmu], d_in[iWlv],
      WmuT, WlvT, 256, 64, mode);
  gemm2_dual<<<dim3(2, 128), 256, 0, stream>>>(hbf, WmuT, WlvT, whmu, whlv);
  transpose_pair<<<dim3(256, 2, 2), 256, 0, stream>>>(whmu, whlv, whmuT, whlvT,
      8192, 64);
  sd_dual<<<dim3(2048, 2), 256, 0, stream>>>(whmu, whlv, d_in[iamu], d_in[ialv],
      smu, slv, dmu, dlv, mode);
  dmax_reduce<<<2, 256, 0, stream>>>(dmu, dlv, dmaxv + 16);
  flash_v3<2><<<256, 512, 0, stream>>>(whmuT, whlvT, smu, dmu, slv, dlv,
      dmaxv + 16, dmaxv + 32, abits,
      muf, out_mu, lvf, out_lv);

  logits_f32<<<256, 256, 0, stream>>>(muf, lvf, d_in[ieps], d_in[iWc], d_in[ibc], out_logits, mode);
}